// Round 1
// baseline (179.031 us; speedup 1.0000x reference)
//
#include <hip/hip_runtime.h>
#include <stdint.h>

// Problem constants
#define BATCH 4096
#define NT    8192          // 2*BATCH
#define FD    256           // feature dim
#define TILE  128           // block tile (TILE x TILE of the pair matrix)
#define NUMK  5

typedef __attribute__((ext_vector_type(8))) short bf16x8;  // 8 bf16 = 4 VGPRs
typedef __attribute__((ext_vector_type(4))) float f32x4;

// ---- workspace layout (bytes) ----
// [0, 4 MiB)            bf16 feats [8192][256]
// WS_SQ    = 4 MiB      sq[8192] f32
// WS_COL   = +32 KiB    colsum[256] f32   (memset 0)
// WS_SUMSQ = +1024      sumsq f32         (memset 0)
static const size_t WS_FB    = 0;
static const size_t WS_SQ    = (size_t)NT * FD * 2;        // 4194304
static const size_t WS_COL   = WS_SQ + (size_t)NT * 4;     // +32768
static const size_t WS_SUMSQ = WS_COL + 256 * 4;           // +1024

__device__ __forceinline__ unsigned short f2bf_rne(float x) {
    unsigned u = __float_as_uint(x);
    unsigned r = (u + 0x7fffu + ((u >> 16) & 1u)) >> 16;
    return (unsigned short)r;
}

// ---------------- kernel 1: convert + row norms + column sums (+ zero out) ----
__global__ void mmd_prep(const float* __restrict__ s_feat,
                         const float* __restrict__ t_feat,
                         unsigned short* __restrict__ fb,
                         float* __restrict__ sq,
                         float* __restrict__ colsum,
                         float* __restrict__ sumsq,
                         float* __restrict__ out) {
    __shared__ float cp[4][FD];
    // zero the scalar output (device-scope atomic store; mmd_main's atomics
    // are ordered after this kernel by the stream dependency)
    if (blockIdx.x == 0 && threadIdx.x == 0) atomicExch(out, 0.0f);
    const int w    = threadIdx.x >> 6;
    const int lane = threadIdx.x & 63;
    float c0 = 0.f, c1 = 0.f, c2 = 0.f, c3 = 0.f;
    float wtot = 0.f;
    for (int t = 0; t < 8; ++t) {
        int row = blockIdx.x * 32 + w * 8 + t;
        const float* src = (row < BATCH) ? (s_feat + (size_t)row * FD)
                                         : (t_feat + (size_t)(row - BATCH) * FD);
        float4 v = ((const float4*)src)[lane];
        unsigned int u01 = (unsigned)f2bf_rne(v.x) | ((unsigned)f2bf_rne(v.y) << 16);
        unsigned int u23 = (unsigned)f2bf_rne(v.z) | ((unsigned)f2bf_rne(v.w) << 16);
        ((uint2*)(fb + (size_t)row * FD))[lane] = make_uint2(u01, u23);
        float ss = v.x * v.x + v.y * v.y + v.z * v.z + v.w * v.w;
        for (int off = 32; off; off >>= 1) ss += __shfl_down(ss, off);
        if (lane == 0) { sq[row] = ss; wtot += ss; }
        c0 += v.x; c1 += v.y; c2 += v.z; c3 += v.w;
    }
    if (lane == 0) atomicAdd(sumsq, wtot);
    cp[w][4 * lane + 0] = c0;
    cp[w][4 * lane + 1] = c1;
    cp[w][4 * lane + 2] = c2;
    cp[w][4 * lane + 3] = c3;
    __syncthreads();
    int t = threadIdx.x;
    float s = cp[0][t] + cp[1][t] + cp[2][t] + cp[3][t];
    atomicAdd(&colsum[t], s);
}

// ---------------- kernel 2: fused gamma + GEMM + gaussian-kernel + reduce ----
// No LDS staging: fb is L2-resident (4 MiB); MFMA fragments are 8 contiguous
// bf16 per lane in the row-major layout, loaded directly with
// global_load_dwordx4. No barriers or vmcnt(0) drains in the K-loop.
__global__ __launch_bounds__(256, 4) void mmd_main(
    const unsigned short* __restrict__ fb,
    const float* __restrict__ sq,
    const float* __restrict__ colsum,
    const float* __restrict__ sumsq,
    float* __restrict__ out) {
    const int bj = blockIdx.x, bi = blockIdx.y;
    if (bj < bi) return;   // upper triangle only (whole-block uniform)

    __shared__ float sqa[TILE], sqb[TILE];
    __shared__ float red[4];
    __shared__ float gsh;

    const int tid  = threadIdx.x;
    const int w    = tid >> 6, lane = tid & 63;
    const int wm   = w & 1, wn = w >> 1;         // 2x2 waves over 128x128
    const int quad = lane >> 4, m16 = lane & 15;

    // ---- inline gamma: bitwise-identical reduction in every block ----
    {
        float c = colsum[tid];
        float v = c * c;
        for (int off = 32; off; off >>= 1) v += __shfl_down(v, off);
        if (lane == 0) red[w] = v;
    }
    if (tid < TILE) sqa[tid] = sq[bi * TILE + tid];
    else            sqb[tid - TILE] = sq[bj * TILE + (tid - TILE)];
    __syncthreads();
    if (tid == 0) {
        float s2 = red[0] + red[1] + red[2] + red[3];
        // sum(distances) = 2*n*sum(sq) - 2*||colsum||^2  (clamp effect negligible)
        float sumd = 2.0f * (float)NT * sumsq[0] - 2.0f * s2;
        float n2n  = (float)((long long)NT * NT - NT);   // n^2 - n
        gsh = 0.25f * (n2n / sumd);   // bw / 2^(NUM_KERNELS//2)
    }
    __syncthreads();
    const float g0 = gsh;

    const f32x4 fzero = {0.f, 0.f, 0.f, 0.f};
    f32x4 acc[4][4];
#pragma unroll
    for (int a = 0; a < 4; ++a)
#pragma unroll
        for (int b = 0; b < 4; ++b) acc[a][b] = fzero;

    // per-lane fragment base pointers (fragment = 8 contiguous bf16 of a row)
    const unsigned short* pa =
        fb + ((size_t)bi * TILE + wm * 64 + m16) * FD + quad * 8;
    const unsigned short* pb =
        fb + ((size_t)bj * TILE + wn * 64 + m16) * FD + quad * 8;

#pragma unroll
    for (int s = 0; s < 8; ++s) {        // k = s*32 .. s*32+31
        bf16x8 af[4], bf[4];
#pragma unroll
        for (int tm = 0; tm < 4; ++tm)
            af[tm] = *(const bf16x8*)(pa + tm * 16 * FD + s * 32);
#pragma unroll
        for (int tn = 0; tn < 4; ++tn)
            bf[tn] = *(const bf16x8*)(pb + tn * 16 * FD + s * 32);
#pragma unroll
        for (int tm = 0; tm < 4; ++tm)
#pragma unroll
            for (int tn = 0; tn < 4; ++tn)
                acc[tm][tn] = __builtin_amdgcn_mfma_f32_16x16x32_bf16(
                    af[tm], bf[tn], acc[tm][tn], 0, 0, 0);
    }

    // ---- epilogue: d = sq_i + sq_j - 2 dot, clamp, e + e^2 + e^4 + e^8 + e^16 ----
    float lsum = 0.f;
#pragma unroll
    for (int tm = 0; tm < 4; ++tm) {
        const int i0 = wm * 64 + tm * 16 + quad * 4;
        float sqi0 = sqa[i0 + 0], sqi1 = sqa[i0 + 1], sqi2 = sqa[i0 + 2], sqi3 = sqa[i0 + 3];
#pragma unroll
        for (int tn = 0; tn < 4; ++tn) {
            const int j = wn * 64 + tn * 16 + m16;
            const float sqj = sqb[j];
            float sqi[4] = {sqi0, sqi1, sqi2, sqi3};
#pragma unroll
            for (int r = 0; r < 4; ++r) {
                float d = fmaf(-2.f, acc[tm][tn][r], sqi[r] + sqj);
                d = fmaxf(d, 0.f);
                float e1 = __expf(-d * g0);
                float e2 = e1 * e1, e4 = e2 * e2, e8 = e4 * e4, e16 = e8 * e8;
                lsum += e1 + e2 + e4 + e8 + e16;
            }
        }
    }
    for (int off = 32; off; off >>= 1) lsum += __shfl_down(lsum, off);
    if (lane == 0) red[w] = lsum;
    __syncthreads();
    if (tid == 0) {
        float wgt;
        if (bi == bj) wgt = 1.f;                                  // diagonal tile, once
        else wgt = ((bi < 32) == (bj < 32)) ? 2.f : -2.f;         // mirrored tile folded in
        // disc = sum / (NUMK * BATCH^2); 1/4096^2 = 2^-24 exact
        float scale = wgt * (1.f / NUMK) * (1.f / 16777216.f);
        atomicAdd(out, (red[0] + red[1] + red[2] + red[3]) * scale);
    }
}

extern "C" void kernel_launch(void* const* d_in, const int* in_sizes, int n_in,
                              void* d_out, int out_size, void* d_ws, size_t ws_size,
                              hipStream_t stream) {
    const float* s_feat = (const float*)d_in[0];
    const float* t_feat = (const float*)d_in[1];
    char* ws = (char*)d_ws;
    unsigned short* fb = (unsigned short*)(ws + WS_FB);
    float* sq     = (float*)(ws + WS_SQ);
    float* colsum = (float*)(ws + WS_COL);
    float* sumsq  = (float*)(ws + WS_SUMSQ);
    float* out    = (float*)d_out;

    hipMemsetAsync(ws + WS_COL, 0, 256 * 4 + 4, stream);  // colsum + sumsq

    mmd_prep<<<NT / 32, 256, 0, stream>>>(s_feat, t_feat, fb, sq, colsum, sumsq, out);
    mmd_main<<<dim3(64, 64), 256, 0, stream>>>(fb, sq, colsum, sumsq, out);
}

// Round 3
// 129.377 us; speedup vs baseline: 1.3838x; 1.3838x over previous
//
#include <hip/hip_runtime.h>
#include <stdint.h>

// Problem constants
#define BATCH 4096
#define NT    8192          // 2*BATCH
#define FD    256           // feature dim
#define TILE  128           // block tile (TILE x TILE of the pair matrix)
#define BK    64            // K chunk per staging step
#define NUMK  5

typedef __attribute__((ext_vector_type(8))) short bf16x8;  // 8 bf16 = 4 VGPRs
typedef __attribute__((ext_vector_type(4))) float f32x4;

// ---- workspace layout (bytes) ----
// [0, 4 MiB)            bf16 feats [8192][256]
// WS_SQ    = 4 MiB      sq[8192] f32
// WS_COL   = +32 KiB    colsum[256] f32   (memset 0)
// WS_SUMSQ = +1024      sumsq f32         (memset 0)
static const size_t WS_FB    = 0;
static const size_t WS_SQ    = (size_t)NT * FD * 2;        // 4194304
static const size_t WS_COL   = WS_SQ + (size_t)NT * 4;     // +32768
static const size_t WS_SUMSQ = WS_COL + 256 * 4;           // +1024

__device__ __forceinline__ unsigned short f2bf_rne(float x) {
    unsigned u = __float_as_uint(x);
    unsigned r = (u + 0x7fffu + ((u >> 16) & 1u)) >> 16;
    return (unsigned short)r;
}

__device__ __forceinline__ void async_copy16(void* lds, const void* g) {
    __builtin_amdgcn_global_load_lds(
        (__attribute__((address_space(1))) void*)(void*)(const_cast<void*>(g)),
        (__attribute__((address_space(3))) void*)lds, 16, 0, 0);
}

// ---------------- kernel 1: convert + row norms + column sums (+ zero out) ----
__global__ void mmd_prep(const float* __restrict__ s_feat,
                         const float* __restrict__ t_feat,
                         unsigned short* __restrict__ fb,
                         float* __restrict__ sq,
                         float* __restrict__ colsum,
                         float* __restrict__ sumsq,
                         float* __restrict__ out) {
    __shared__ float cp[4][FD];
    // zero the scalar output (device-scope atomic store; mmd_main's atomics
    // are ordered after this kernel by the stream dependency)
    if (blockIdx.x == 0 && threadIdx.x == 0) atomicExch(out, 0.0f);
    const int w    = threadIdx.x >> 6;
    const int lane = threadIdx.x & 63;
    float c0 = 0.f, c1 = 0.f, c2 = 0.f, c3 = 0.f;
    float wtot = 0.f;
    for (int t = 0; t < 8; ++t) {
        int row = blockIdx.x * 32 + w * 8 + t;
        const float* src = (row < BATCH) ? (s_feat + (size_t)row * FD)
                                         : (t_feat + (size_t)(row - BATCH) * FD);
        float4 v = ((const float4*)src)[lane];
        unsigned int u01 = (unsigned)f2bf_rne(v.x) | ((unsigned)f2bf_rne(v.y) << 16);
        unsigned int u23 = (unsigned)f2bf_rne(v.z) | ((unsigned)f2bf_rne(v.w) << 16);
        ((uint2*)(fb + (size_t)row * FD))[lane] = make_uint2(u01, u23);
        float ss = v.x * v.x + v.y * v.y + v.z * v.z + v.w * v.w;
        for (int off = 32; off; off >>= 1) ss += __shfl_down(ss, off);
        if (lane == 0) { sq[row] = ss; wtot += ss; }
        c0 += v.x; c1 += v.y; c2 += v.z; c3 += v.w;
    }
    if (lane == 0) atomicAdd(sumsq, wtot);
    cp[w][4 * lane + 0] = c0;
    cp[w][4 * lane + 1] = c1;
    cp[w][4 * lane + 2] = c2;
    cp[w][4 * lane + 3] = c3;
    __syncthreads();
    int t = threadIdx.x;
    float s = cp[0][t] + cp[1][t] + cp[2][t] + cp[3][t];
    atomicAdd(&colsum[t], s);
}

// ---------------- kernel 2: fused gamma + GEMM + gaussian-kernel + reduce ----
// Round-0 LDS structure + cross-tile prefetch double-buffering:
//   STAGE(next buf) -> ds_read+MFMA(cur buf) -> barrier(vmcnt drain)
// One barrier per K-tile (4 total); stage latency hides under the previous
// tile's 32-MFMA compute phase.
__global__ __launch_bounds__(256, 2) void mmd_main(
    const unsigned short* __restrict__ fb,
    const float* __restrict__ sq,
    const float* __restrict__ colsum,
    const float* __restrict__ sumsq,
    float* __restrict__ out) {
    const int bj = blockIdx.x, bi = blockIdx.y;
    if (bj < bi) return;   // upper triangle only (whole-block uniform)

    __shared__ __align__(16) unsigned short a_t[2][TILE * BK];
    __shared__ __align__(16) unsigned short b_t[2][TILE * BK];
    __shared__ float sqa[TILE], sqb[TILE];
    __shared__ float red[4];

    const int tid  = threadIdx.x;
    const int w    = tid >> 6, lane = tid & 63;
    const int wm   = w & 1, wn = w >> 1;         // 2x2 waves over 128x128
    const int quad = lane >> 4, m16 = lane & 15;
    const int lrow   = lane >> 3;                // 0..7 (row within 8-row group)
    const int lchunk = lane & 7;                 // physical 16B-chunk slot
    const int gc = lchunk ^ lrow;   // XOR-swizzle: slot p holds global chunk p^(row&7)

    const size_t rowA0 = (size_t)bi * TILE;
    const size_t rowB0 = (size_t)bj * TILE;

#define STAGE(buf, k0_) do {                                                   \
        _Pragma("unroll")                                                      \
        for (int q = 0; q < 4; ++q) {                                          \
            int r = q * 32 + w * 8 + lrow;   /* (r & 7) == lrow */             \
            async_copy16(&a_t[buf][(q * 32 + w * 8) * BK],                     \
                         fb + (rowA0 + r) * FD + (k0_) + gc * 8);              \
        }                                                                      \
        _Pragma("unroll")                                                      \
        for (int q = 0; q < 4; ++q) {                                          \
            int r = q * 32 + w * 8 + lrow;                                     \
            async_copy16(&b_t[buf][(q * 32 + w * 8) * BK],                     \
                         fb + (rowB0 + r) * FD + (k0_) + gc * 8);              \
        }                                                                      \
    } while (0)

    // issue tile-0 staging ASAP; its latency hides under the setup below
    STAGE(0, 0);

    // ---- inline gamma: per-wave butterfly, identical in every wave/block ----
    float4 c4 = ((const float4*)colsum)[lane];       // 64 lanes x 4 = 256 cols
    float cv = c4.x * c4.x + c4.y * c4.y + c4.z * c4.z + c4.w * c4.w;
    for (int off = 1; off < 64; off <<= 1) cv += __shfl_xor(cv, off);
    // sum(distances) = 2*n*sum(sq) - 2*||colsum||^2  (clamp effect negligible)
    const float sumd = 2.0f * (float)NT * sumsq[0] - 2.0f * cv;
    const float n2n  = (float)((long long)NT * NT - NT);   // n^2 - n
    const float g0   = 0.25f * (n2n / sumd);   // bw / 2^(NUM_KERNELS//2)

    if (tid < TILE) sqa[tid] = sq[bi * TILE + tid];
    else            sqb[tid - TILE] = sq[bj * TILE + (tid - TILE)];

    const f32x4 fzero = {0.f, 0.f, 0.f, 0.f};
    f32x4 acc[4][4];
#pragma unroll
    for (int a = 0; a < 4; ++a)
#pragma unroll
        for (int b = 0; b < 4; ++b) acc[a][b] = fzero;

    __syncthreads();   // drains vmcnt: tile-0 staged; sqa/sqb visible

#pragma unroll
    for (int st = 0; st < 4; ++st) {
        const int cur = st & 1;
        if (st < 3) STAGE(cur ^ 1, (st + 1) * BK);   // prefetch next K-tile

#pragma unroll
        for (int kk = 0; kk < BK; kk += 32) {
            bf16x8 af[4], bf[4];
            const int cl = (kk >> 3) + quad;   // logical 16B chunk 0..7
#pragma unroll
            for (int tm = 0; tm < 4; ++tm) {
                int row = wm * 64 + tm * 16 + m16;
                int p = cl ^ (row & 7);
                af[tm] = *(const bf16x8*)&a_t[cur][row * BK + p * 8];
            }
#pragma unroll
            for (int tn = 0; tn < 4; ++tn) {
                int row = wn * 64 + tn * 16 + m16;
                int p = cl ^ (row & 7);
                bf[tn] = *(const bf16x8*)&b_t[cur][row * BK + p * 8];
            }
#pragma unroll
            for (int tm = 0; tm < 4; ++tm)
#pragma unroll
                for (int tn = 0; tn < 4; ++tn)
                    acc[tm][tn] = __builtin_amdgcn_mfma_f32_16x16x32_bf16(
                        af[tm], bf[tn], acc[tm][tn], 0, 0, 0);
        }
        // barrier drains vmcnt (prefetch complete) and orders this tile's
        // LDS reads before the buffer is overwritten next iteration
        if (st < 3) __syncthreads();
    }

    // ---- epilogue: d = sq_i + sq_j - 2 dot, clamp, e + e^2 + e^4 + e^8 + e^16 ----
    float lsum = 0.f;
#pragma unroll
    for (int tm = 0; tm < 4; ++tm) {
        const int i0 = wm * 64 + tm * 16 + quad * 4;
        float sqi0 = sqa[i0 + 0], sqi1 = sqa[i0 + 1], sqi2 = sqa[i0 + 2], sqi3 = sqa[i0 + 3];
#pragma unroll
        for (int tn = 0; tn < 4; ++tn) {
            const int j = wn * 64 + tn * 16 + m16;
            const float sqj = sqb[j];
            float sqi[4] = {sqi0, sqi1, sqi2, sqi3};
#pragma unroll
            for (int r = 0; r < 4; ++r) {
                float d = fmaf(-2.f, acc[tm][tn][r], sqi[r] + sqj);
                d = fmaxf(d, 0.f);
                float e1 = __expf(-d * g0);
                float e2 = e1 * e1, e4 = e2 * e2, e8 = e4 * e4, e16 = e8 * e8;
                lsum += e1 + e2 + e4 + e8 + e16;
            }
        }
    }
    for (int off = 32; off; off >>= 1) lsum += __shfl_down(lsum, off);
    if (lane == 0) red[w] = lsum;
    __syncthreads();
    if (tid == 0) {
        float wgt;
        if (bi == bj) wgt = 1.f;                                  // diagonal tile, once
        else wgt = ((bi < 32) == (bj < 32)) ? 2.f : -2.f;         // mirrored tile folded in
        // disc = sum / (NUMK * BATCH^2); 1/4096^2 = 2^-24 exact
        float scale = wgt * (1.f / NUMK) * (1.f / 16777216.f);
        atomicAdd(out, (red[0] + red[1] + red[2] + red[3]) * scale);
    }
}

extern "C" void kernel_launch(void* const* d_in, const int* in_sizes, int n_in,
                              void* d_out, int out_size, void* d_ws, size_t ws_size,
                              hipStream_t stream) {
    const float* s_feat = (const float*)d_in[0];
    const float* t_feat = (const float*)d_in[1];
    char* ws = (char*)d_ws;
    unsigned short* fb = (unsigned short*)(ws + WS_FB);
    float* sq     = (float*)(ws + WS_SQ);
    float* colsum = (float*)(ws + WS_COL);
    float* sumsq  = (float*)(ws + WS_SUMSQ);
    float* out    = (float*)d_out;

    hipMemsetAsync(ws + WS_COL, 0, 256 * 4 + 4, stream);  // colsum + sumsq

    mmd_prep<<<NT / 32, 256, 0, stream>>>(s_feat, t_feat, fb, sq, colsum, sumsq, out);
    mmd_main<<<dim3(64, 64), 256, 0, stream>>>(fb, sq, colsum, sumsq, out);
}

// Round 4
// 119.741 us; speedup vs baseline: 1.4952x; 1.0805x over previous
//
#include <hip/hip_runtime.h>
#include <stdint.h>
#include <math.h>

// Problem constants
#define BATCH 4096
#define NT    8192          // 2*BATCH
#define FD    256           // feature dim
#define TILE  128           // block tile (TILE x TILE of the pair matrix)
#define BK    32            // K chunk per staging step (8 steps, triple-buffered)
#define NUMK  5

typedef __attribute__((ext_vector_type(8))) short bf16x8;  // 8 bf16 = 4 VGPRs
typedef __attribute__((ext_vector_type(4))) float f32x4;

// ---- workspace layout (bytes) ----
static const size_t WS_FB    = 0;
static const size_t WS_SQ    = (size_t)NT * FD * 2;        // 4194304
static const size_t WS_COL   = WS_SQ + (size_t)NT * 4;     // +32768
static const size_t WS_SUMSQ = WS_COL + 256 * 4;           // +1024

__device__ __forceinline__ unsigned short f2bf_rne(float x) {
    unsigned u = __float_as_uint(x);
    unsigned r = (u + 0x7fffu + ((u >> 16) & 1u)) >> 16;
    return (unsigned short)r;
}

__device__ __forceinline__ void async_copy16(void* lds, const void* g) {
    __builtin_amdgcn_global_load_lds(
        (__attribute__((address_space(1))) void*)(void*)(const_cast<void*>(g)),
        (__attribute__((address_space(3))) void*)lds, 16, 0, 0);
}

// ---------------- kernel 1: convert + row norms + column sums (+ zero out) ----
__global__ void mmd_prep(const float* __restrict__ s_feat,
                         const float* __restrict__ t_feat,
                         unsigned short* __restrict__ fb,
                         float* __restrict__ sq,
                         float* __restrict__ colsum,
                         float* __restrict__ sumsq,
                         float* __restrict__ out) {
    __shared__ float cp[4][FD];
    if (blockIdx.x == 0 && threadIdx.x == 0) atomicExch(out, 0.0f);
    const int w    = threadIdx.x >> 6;
    const int lane = threadIdx.x & 63;
    float c0 = 0.f, c1 = 0.f, c2 = 0.f, c3 = 0.f;
    float wtot = 0.f;
    for (int t = 0; t < 8; ++t) {
        int row = blockIdx.x * 32 + w * 8 + t;
        const float* src = (row < BATCH) ? (s_feat + (size_t)row * FD)
                                         : (t_feat + (size_t)(row - BATCH) * FD);
        float4 v = ((const float4*)src)[lane];
        unsigned int u01 = (unsigned)f2bf_rne(v.x) | ((unsigned)f2bf_rne(v.y) << 16);
        unsigned int u23 = (unsigned)f2bf_rne(v.z) | ((unsigned)f2bf_rne(v.w) << 16);
        ((uint2*)(fb + (size_t)row * FD))[lane] = make_uint2(u01, u23);
        float ss = v.x * v.x + v.y * v.y + v.z * v.z + v.w * v.w;
        for (int off = 32; off; off >>= 1) ss += __shfl_down(ss, off);
        if (lane == 0) { sq[row] = ss; wtot += ss; }
        c0 += v.x; c1 += v.y; c2 += v.z; c3 += v.w;
    }
    if (lane == 0) atomicAdd(sumsq, wtot);
    cp[w][4 * lane + 0] = c0;
    cp[w][4 * lane + 1] = c1;
    cp[w][4 * lane + 2] = c2;
    cp[w][4 * lane + 3] = c3;
    __syncthreads();
    int t = threadIdx.x;
    float s = cp[0][t] + cp[1][t] + cp[2][t] + cp[3][t];
    atomicAdd(&colsum[t], s);
}

// ---------------- kernel 2: fused gamma + GEMM + gaussian-kernel + reduce ----
// Triple-buffered BK=32 pipeline with counted vmcnt (T3+T4):
//   step st: [vmcnt(4) certify buf[st%3]] -> s_barrier -> ds_read buf[st%3]
//            -> issue STAGE(buf[(st+2)%3]) -> setprio(1) MFMA x16 setprio(0)
// Loads stay 2 steps in flight; no vmcnt(0) drain in the main loop.
// LDS 50 KB -> 3 blocks/CU for cross-block latency hiding.
__global__ __launch_bounds__(256, 4) void mmd_main(
    const unsigned short* __restrict__ fb,
    const float* __restrict__ sq,
    const float* __restrict__ colsum,
    const float* __restrict__ sumsq,
    float* __restrict__ out) {
    // exact-triangle grid: decode linear bid -> (bi <= bj)
    const int bid = blockIdx.x;
    int r = (int)((sqrtf(8.0f * (float)bid + 1.0f) - 1.0f) * 0.5f);
    while ((r + 1) * (r + 2) / 2 <= bid) ++r;
    while (r * (r + 1) / 2 > bid) --r;
    const int bi = bid - r * (r + 1) / 2;   // 0..r
    const int bj = r;

    __shared__ __align__(16) unsigned short a_t[3][TILE * BK];  // 3 x 8 KiB
    __shared__ __align__(16) unsigned short b_t[3][TILE * BK];  // 3 x 8 KiB
    __shared__ float sqa[TILE], sqb[TILE];
    __shared__ float red[4];

    const int tid  = threadIdx.x;
    const int w    = tid >> 6, lane = tid & 63;
    const int wm   = w & 1, wn = w >> 1;         // 2x2 waves over 128x128
    const int quad = lane >> 4, m16 = lane & 15;
    const int lrow16 = lane >> 2;                // 0..15 (row within 16-row group)
    const int pslot  = lane & 3;                 // physical 16B slot within 64B row

    const size_t rowA0 = (size_t)bi * TILE;
    const size_t rowB0 = (size_t)bj * TILE;

    // Swizzle: physical slot p of row r holds global chunk p ^ ((r>>1)&3).
    // Read side inverts with the same XOR; per 8-row group all 16B slots are
    // distinct -> 2 lanes/bank (free, m136).
#define STAGE(buf, k0_) do {                                                   \
        _Pragma("unroll")                                                      \
        for (int q = 0; q < 2; ++q) {                                          \
            int rr = w * 32 + q * 16 + lrow16;                                 \
            int gcq = pslot ^ ((rr >> 1) & 3);                                 \
            async_copy16(&a_t[buf][(w * 32 + q * 16) * BK],                    \
                         fb + (rowA0 + rr) * FD + (k0_) + gcq * 8);            \
        }                                                                      \
        _Pragma("unroll")                                                      \
        for (int q = 0; q < 2; ++q) {                                          \
            int rr = w * 32 + q * 16 + lrow16;                                 \
            int gcq = pslot ^ ((rr >> 1) & 3);                                 \
            async_copy16(&b_t[buf][(w * 32 + q * 16) * BK],                    \
                         fb + (rowB0 + rr) * FD + (k0_) + gcq * 8);            \
        }                                                                      \
    } while (0)

    // prologue: fill buffers 0 and 1 (drained by the single __syncthreads below)
    STAGE(0, 0);
    STAGE(1, BK);

    // ---- inline gamma: per-wave butterfly, identical in every wave/block ----
    float4 c4 = ((const float4*)colsum)[lane];       // 64 lanes x 4 = 256 cols
    float cv = c4.x * c4.x + c4.y * c4.y + c4.z * c4.z + c4.w * c4.w;
    for (int off = 1; off < 64; off <<= 1) cv += __shfl_xor(cv, off);
    const float sumd = 2.0f * (float)NT * sumsq[0] - 2.0f * cv;
    const float n2n  = (float)((long long)NT * NT - NT);   // n^2 - n
    const float g0   = 0.25f * (n2n / sumd);   // bw / 2^(NUM_KERNELS//2)

    if (tid < TILE) sqa[tid] = sq[bi * TILE + tid];
    else            sqb[tid - TILE] = sq[bj * TILE + (tid - TILE)];

    const f32x4 fzero = {0.f, 0.f, 0.f, 0.f};
    f32x4 acc[4][4];
#pragma unroll
    for (int a = 0; a < 4; ++a)
#pragma unroll
        for (int b = 0; b < 4; ++b) acc[a][b] = fzero;

    __syncthreads();   // full drain once: buf0+buf1 staged, sqa/sqb visible

#pragma unroll
    for (int st = 0; st < 8; ++st) {
        // certify this step's buffer: its loads were issued 2 steps ago.
        // steady state keeps the newest 4 loads (next buffer) in flight.
        if (st >= 2) {
            if (st == 7) asm volatile("s_waitcnt vmcnt(0)" ::: "memory");
            else         asm volatile("s_waitcnt vmcnt(4)" ::: "memory");
        }
        if (st > 0) {
            __builtin_amdgcn_s_barrier();        // publish: prev step's reads done
            __builtin_amdgcn_sched_barrier(0);   // nothing crosses the barrier
        }
        const int cur = st % 3;   // compile-time after full unroll

        bf16x8 af[4], bf[4];
#pragma unroll
        for (int tm = 0; tm < 4; ++tm) {
            int row = wm * 64 + tm * 16 + m16;
            int p = quad ^ ((row >> 1) & 3);
            af[tm] = *(const bf16x8*)&a_t[cur][row * BK + p * 8];
        }
#pragma unroll
        for (int tn = 0; tn < 4; ++tn) {
            int row = wn * 64 + tn * 16 + m16;
            int p = quad ^ ((row >> 1) & 3);
            bf[tn] = *(const bf16x8*)&b_t[cur][row * BK + p * 8];
        }

        if (st < 6) STAGE((st + 2) % 3, (st + 2) * BK);   // 2-ahead prefetch

        __builtin_amdgcn_s_setprio(1);
#pragma unroll
        for (int tm = 0; tm < 4; ++tm)
#pragma unroll
            for (int tn = 0; tn < 4; ++tn)
                acc[tm][tn] = __builtin_amdgcn_mfma_f32_16x16x32_bf16(
                    af[tm], bf[tn], acc[tm][tn], 0, 0, 0);
        __builtin_amdgcn_s_setprio(0);
    }

    // ---- epilogue: d = sq_i + sq_j - 2 dot, clamp, e + e^2 + e^4 + e^8 + e^16 ----
    float lsum = 0.f;
#pragma unroll
    for (int tm = 0; tm < 4; ++tm) {
        const int i0 = wm * 64 + tm * 16 + quad * 4;
        float sqi0 = sqa[i0 + 0], sqi1 = sqa[i0 + 1], sqi2 = sqa[i0 + 2], sqi3 = sqa[i0 + 3];
#pragma unroll
        for (int tn = 0; tn < 4; ++tn) {
            const int j = wn * 64 + tn * 16 + m16;
            const float sqj = sqb[j];
            float sqi[4] = {sqi0, sqi1, sqi2, sqi3};
#pragma unroll
            for (int rr = 0; rr < 4; ++rr) {
                float d = fmaf(-2.f, acc[tm][tn][rr], sqi[rr] + sqj);
                d = fmaxf(d, 0.f);
                float e1 = __expf(-d * g0);
                float e2 = e1 * e1, e4 = e2 * e2, e8 = e4 * e4, e16 = e8 * e8;
                lsum += e1 + e2 + e4 + e8 + e16;
            }
        }
    }
    for (int off = 32; off; off >>= 1) lsum += __shfl_down(lsum, off);
    if (lane == 0) red[w] = lsum;
    __syncthreads();
    if (tid == 0) {
        float wgt;
        if (bi == bj) wgt = 1.f;                                  // diagonal tile, once
        else wgt = ((bi < 32) == (bj < 32)) ? 2.f : -2.f;         // mirrored tile folded in
        float scale = wgt * (1.f / NUMK) * (1.f / 16777216.f);    // /(NUMK*4096^2)
        atomicAdd(out, (red[0] + red[1] + red[2] + red[3]) * scale);
    }
}

extern "C" void kernel_launch(void* const* d_in, const int* in_sizes, int n_in,
                              void* d_out, int out_size, void* d_ws, size_t ws_size,
                              hipStream_t stream) {
    const float* s_feat = (const float*)d_in[0];
    const float* t_feat = (const float*)d_in[1];
    char* ws = (char*)d_ws;
    unsigned short* fb = (unsigned short*)(ws + WS_FB);
    float* sq     = (float*)(ws + WS_SQ);
    float* colsum = (float*)(ws + WS_COL);
    float* sumsq  = (float*)(ws + WS_SUMSQ);
    float* out    = (float*)d_out;

    hipMemsetAsync(ws + WS_COL, 0, 256 * 4 + 4, stream);  // colsum + sumsq

    mmd_prep<<<NT / 32, 256, 0, stream>>>(s_feat, t_feat, fb, sq, colsum, sumsq, out);
    mmd_main<<<2080, 256, 0, stream>>>(fb, sq, colsum, sumsq, out);  // exact triangle
}

// Round 5
// 119.547 us; speedup vs baseline: 1.4976x; 1.0016x over previous
//
#include <hip/hip_runtime.h>
#include <stdint.h>
#include <math.h>

// Problem constants
#define BATCH 4096
#define NT    8192          // 2*BATCH
#define FD    256           // feature dim
#define TILE  128           // block tile (TILE x TILE of the pair matrix)
#define BK    32            // K chunk per staging step (8 steps, triple-buffered)
#define NUMK  5

typedef __attribute__((ext_vector_type(8))) short bf16x8;  // 8 bf16 = 4 VGPRs
typedef __attribute__((ext_vector_type(4))) float f32x4;

// ---- workspace layout (bytes) ----
static const size_t WS_FB    = 0;
static const size_t WS_SQ    = (size_t)NT * FD * 2;        // 4194304
static const size_t WS_COL   = WS_SQ + (size_t)NT * 4;     // +32768
static const size_t WS_SUMSQ = WS_COL + 256 * 4;           // +1024

__device__ __forceinline__ unsigned short f2bf_rne(float x) {
    unsigned u = __float_as_uint(x);
    unsigned r = (u + 0x7fffu + ((u >> 16) & 1u)) >> 16;
    return (unsigned short)r;
}

__device__ __forceinline__ void async_copy16(void* lds, const void* g) {
    __builtin_amdgcn_global_load_lds(
        (__attribute__((address_space(1))) void*)(void*)(const_cast<void*>(g)),
        (__attribute__((address_space(3))) void*)lds, 16, 0, 0);
}

// ---------------- kernel 1: convert + row norms + column sums (+ zero out) ----
__global__ void mmd_prep(const float* __restrict__ s_feat,
                         const float* __restrict__ t_feat,
                         unsigned short* __restrict__ fb,
                         float* __restrict__ sq,
                         float* __restrict__ colsum,
                         float* __restrict__ sumsq,
                         float* __restrict__ out) {
    __shared__ float cp[4][FD];
    if (blockIdx.x == 0 && threadIdx.x == 0) atomicExch(out, 0.0f);
    const int w    = threadIdx.x >> 6;
    const int lane = threadIdx.x & 63;
    float c0 = 0.f, c1 = 0.f, c2 = 0.f, c3 = 0.f;
    float wtot = 0.f;
    for (int t = 0; t < 8; ++t) {
        int row = blockIdx.x * 32 + w * 8 + t;
        const float* src = (row < BATCH) ? (s_feat + (size_t)row * FD)
                                         : (t_feat + (size_t)(row - BATCH) * FD);
        float4 v = ((const float4*)src)[lane];
        unsigned int u01 = (unsigned)f2bf_rne(v.x) | ((unsigned)f2bf_rne(v.y) << 16);
        unsigned int u23 = (unsigned)f2bf_rne(v.z) | ((unsigned)f2bf_rne(v.w) << 16);
        ((uint2*)(fb + (size_t)row * FD))[lane] = make_uint2(u01, u23);
        float ss = v.x * v.x + v.y * v.y + v.z * v.z + v.w * v.w;
        for (int off = 32; off; off >>= 1) ss += __shfl_down(ss, off);
        if (lane == 0) { sq[row] = ss; wtot += ss; }
        c0 += v.x; c1 += v.y; c2 += v.z; c3 += v.w;
    }
    if (lane == 0) atomicAdd(sumsq, wtot);
    cp[w][4 * lane + 0] = c0;
    cp[w][4 * lane + 1] = c1;
    cp[w][4 * lane + 2] = c2;
    cp[w][4 * lane + 3] = c3;
    __syncthreads();
    int t = threadIdx.x;
    float s = cp[0][t] + cp[1][t] + cp[2][t] + cp[3][t];
    atomicAdd(&colsum[t], s);
}

// ---------------- kernel 2: fused gamma + GEMM + gaussian-kernel + reduce ----
// Triple-buffered BK=32 pipeline (counted vmcnt) + register ping-pong frags:
//   step st: STAGE(st+2) -> vmcnt(4) -> barrier -> ds_read frags[st+1]
//            -> setprio(1) MFMA(frags[st]) setprio(0)
// MFMAs never wait on this step's ds_reads; LDS latency spans a full step.
__global__ __launch_bounds__(256, 3) void mmd_main(
    const unsigned short* __restrict__ fb,
    const float* __restrict__ sq,
    const float* __restrict__ colsum,
    const float* __restrict__ sumsq,
    float* __restrict__ out) {
    // exact-triangle grid: decode linear bid -> (bi <= bj)
    const int bid = blockIdx.x;
    int r = (int)((sqrtf(8.0f * (float)bid + 1.0f) - 1.0f) * 0.5f);
    while ((r + 1) * (r + 2) / 2 <= bid) ++r;
    while (r * (r + 1) / 2 > bid) --r;
    const int bi = bid - r * (r + 1) / 2;   // 0..r
    const int bj = r;

    __shared__ __align__(16) unsigned short a_t[3][TILE * BK];  // 3 x 8 KiB
    __shared__ __align__(16) unsigned short b_t[3][TILE * BK];  // 3 x 8 KiB
    __shared__ float sqa[TILE], sqb[TILE];
    __shared__ float red[4];

    const int tid  = threadIdx.x;
    const int w    = tid >> 6, lane = tid & 63;
    const int wm   = w & 1, wn = w >> 1;         // 2x2 waves over 128x128
    const int quad = lane >> 4, m16 = lane & 15;
    const int lrow16 = lane >> 2;                // 0..15 (row within 16-row group)
    const int pslot  = lane & 3;                 // physical 16B slot within 64B row

    const size_t rowA0 = (size_t)bi * TILE;
    const size_t rowB0 = (size_t)bj * TILE;

    // Swizzle: physical slot p of row r holds global chunk p ^ ((r>>1)&3).
#define STAGE(buf, k0_) do {                                                   \
        _Pragma("unroll")                                                      \
        for (int q = 0; q < 2; ++q) {                                          \
            int rr = w * 32 + q * 16 + lrow16;                                 \
            int gcq = pslot ^ ((rr >> 1) & 3);                                 \
            async_copy16(&a_t[buf][(w * 32 + q * 16) * BK],                    \
                         fb + (rowA0 + rr) * FD + (k0_) + gcq * 8);            \
        }                                                                      \
        _Pragma("unroll")                                                      \
        for (int q = 0; q < 2; ++q) {                                          \
            int rr = w * 32 + q * 16 + lrow16;                                 \
            int gcq = pslot ^ ((rr >> 1) & 3);                                 \
            async_copy16(&b_t[buf][(w * 32 + q * 16) * BK],                    \
                         fb + (rowB0 + rr) * FD + (k0_) + gcq * 8);            \
        }                                                                      \
    } while (0)

    // prologue: fill buffers 0 and 1 (drained by the single __syncthreads below)
    STAGE(0, 0);
    STAGE(1, BK);

    // ---- inline gamma: per-wave butterfly, identical in every wave/block ----
    float4 c4 = ((const float4*)colsum)[lane];       // 64 lanes x 4 = 256 cols
    float cv = c4.x * c4.x + c4.y * c4.y + c4.z * c4.z + c4.w * c4.w;
    for (int off = 1; off < 64; off <<= 1) cv += __shfl_xor(cv, off);
    const float sumd = 2.0f * (float)NT * sumsq[0] - 2.0f * cv;
    const float n2n  = (float)((long long)NT * NT - NT);   // n^2 - n
    const float g0   = 0.25f * (n2n / sumd);   // bw / 2^(NUM_KERNELS//2)

    if (tid < TILE) sqa[tid] = sq[bi * TILE + tid];
    else            sqb[tid - TILE] = sq[bj * TILE + (tid - TILE)];

    const f32x4 fzero = {0.f, 0.f, 0.f, 0.f};
    f32x4 acc[4][4];
#pragma unroll
    for (int a = 0; a < 4; ++a)
#pragma unroll
        for (int b = 0; b < 4; ++b) acc[a][b] = fzero;

    __syncthreads();   // full drain once: buf0+buf1 staged + certified, sqa/sqb visible

    // register ping-pong fragments; all indices compile-time after full unroll
    bf16x8 af[2][4], bf[2][4];
#pragma unroll
    for (int tm = 0; tm < 4; ++tm) {
        int row = wm * 64 + tm * 16 + m16;
        int p = quad ^ ((row >> 1) & 3);
        af[0][tm] = *(const bf16x8*)&a_t[0][row * BK + p * 8];
    }
#pragma unroll
    for (int tn = 0; tn < 4; ++tn) {
        int row = wn * 64 + tn * 16 + m16;
        int p = quad ^ ((row >> 1) & 3);
        bf[0][tn] = *(const bf16x8*)&b_t[0][row * BK + p * 8];
    }

#pragma unroll
    for (int st = 0; st < 8; ++st) {
        const int cur = st & 1, nxt = cur ^ 1;

        if (st < 6) STAGE((st + 2) % 3, (st + 2) * BK);   // 2-ahead prefetch

        if (st >= 1 && st < 7) {
            // certify buf[(st+1)%3]: its STAGE was issued at step st-1.
            // outstanding here: STAGE(st+1) + STAGE(st+2) = 8 (st<=5); 4 at st=6.
            if (st == 6) asm volatile("s_waitcnt vmcnt(0)" ::: "memory");
            else         asm volatile("s_waitcnt vmcnt(4)" ::: "memory");
            __builtin_amdgcn_s_barrier();        // publish buf[st+1] to all waves
            __builtin_amdgcn_sched_barrier(0);   // reads below must not hoist
        }

        if (st < 7) {   // issue next step's fragment reads (consumed next step)
            const int bn = (st + 1) % 3;
#pragma unroll
            for (int tm = 0; tm < 4; ++tm) {
                int row = wm * 64 + tm * 16 + m16;
                int p = quad ^ ((row >> 1) & 3);
                af[nxt][tm] = *(const bf16x8*)&a_t[bn][row * BK + p * 8];
            }
#pragma unroll
            for (int tn = 0; tn < 4; ++tn) {
                int row = wn * 64 + tn * 16 + m16;
                int p = quad ^ ((row >> 1) & 3);
                bf[nxt][tn] = *(const bf16x8*)&b_t[bn][row * BK + p * 8];
            }
        }
        __builtin_amdgcn_sched_barrier(0);       // keep reads above the MFMA cluster

        __builtin_amdgcn_s_setprio(1);
#pragma unroll
        for (int tm = 0; tm < 4; ++tm)
#pragma unroll
            for (int tn = 0; tn < 4; ++tn)
                acc[tm][tn] = __builtin_amdgcn_mfma_f32_16x16x32_bf16(
                    af[cur][tm], bf[cur][tn], acc[tm][tn], 0, 0, 0);
        __builtin_amdgcn_s_setprio(0);
    }

    // ---- epilogue: d = sq_i + sq_j - 2 dot, clamp, e + e^2 + e^4 + e^8 + e^16 ----
    float lsum = 0.f;
#pragma unroll
    for (int tm = 0; tm < 4; ++tm) {
        const int i0 = wm * 64 + tm * 16 + quad * 4;
        float sqi0 = sqa[i0 + 0], sqi1 = sqa[i0 + 1], sqi2 = sqa[i0 + 2], sqi3 = sqa[i0 + 3];
#pragma unroll
        for (int tn = 0; tn < 4; ++tn) {
            const int j = wn * 64 + tn * 16 + m16;
            const float sqj = sqb[j];
            float sqi[4] = {sqi0, sqi1, sqi2, sqi3};
#pragma unroll
            for (int rr = 0; rr < 4; ++rr) {
                float d = fmaf(-2.f, acc[tm][tn][rr], sqi[rr] + sqj);
                d = fmaxf(d, 0.f);
                float e1 = __expf(-d * g0);
                float e2 = e1 * e1, e4 = e2 * e2, e8 = e4 * e4, e16 = e8 * e8;
                lsum += e1 + e2 + e4 + e8 + e16;
            }
        }
    }
    for (int off = 32; off; off >>= 1) lsum += __shfl_down(lsum, off);
    if (lane == 0) red[w] = lsum;
    __syncthreads();
    if (tid == 0) {
        float wgt;
        if (bi == bj) wgt = 1.f;                                  // diagonal tile, once
        else wgt = ((bi < 32) == (bj < 32)) ? 2.f : -2.f;         // mirrored tile folded in
        float scale = wgt * (1.f / NUMK) * (1.f / 16777216.f);    // /(NUMK*4096^2)
        atomicAdd(out, (red[0] + red[1] + red[2] + red[3]) * scale);
    }
}

extern "C" void kernel_launch(void* const* d_in, const int* in_sizes, int n_in,
                              void* d_out, int out_size, void* d_ws, size_t ws_size,
                              hipStream_t stream) {
    const float* s_feat = (const float*)d_in[0];
    const float* t_feat = (const float*)d_in[1];
    char* ws = (char*)d_ws;
    unsigned short* fb = (unsigned short*)(ws + WS_FB);
    float* sq     = (float*)(ws + WS_SQ);
    float* colsum = (float*)(ws + WS_COL);
    float* sumsq  = (float*)(ws + WS_SUMSQ);
    float* out    = (float*)d_out;

    hipMemsetAsync(ws + WS_COL, 0, 256 * 4 + 4, stream);  // colsum + sumsq

    mmd_prep<<<NT / 32, 256, 0, stream>>>(s_feat, t_feat, fb, sq, colsum, sumsq, out);
    mmd_main<<<2080, 256, 0, stream>>>(fb, sq, colsum, sumsq, out);  // exact triangle
}